// Round 8
// baseline (178.261 us; speedup 1.0000x reference)
//
#include <hip/hip_runtime.h>
#include <math.h>

// Problem constants (N=2, C=256, H=W=64, G=8, P=9, CG=32)
#define CC    256
#define HH    64
#define WW    64
#define HWSZ  4096
#define NPIX  8192
#define MT    16        // conv_in tile (pixels)
#define TT    16        // tail tile (pixels) — full MFMA A-tile, 64-B store lines
#define ASTR  264       // A-tile LDS row stride in bf16 elems (528 B)

typedef __attribute__((ext_vector_type(8))) short short8;
typedef __attribute__((ext_vector_type(4))) float f32x4;

__device__ __forceinline__ float silu_f(float x) { return x / (1.f + __expf(-x)); }

// fp32 -> bf16 round-to-nearest-even
__device__ __forceinline__ short f2bf(float f) {
    unsigned u = __float_as_uint(f);
    unsigned r = (u + 0x7fffu + ((u >> 16) & 1u)) >> 16;
    return (short)r;
}
__device__ __forceinline__ unsigned pk2(float a, float b) {
    return (unsigned)(unsigned short)f2bf(a) | ((unsigned)(unsigned short)f2bf(b) << 16);
}
// 4 packed bf16 -> float4
__device__ __forceinline__ float4 bf4(uint2 u) {
    float4 r;
    r.x = __uint_as_float(u.x << 16);
    r.y = __uint_as_float(u.x & 0xffff0000u);
    r.z = __uint_as_float(u.y << 16);
    r.w = __uint_as_float(u.y & 0xffff0000u);
    return r;
}
// 8 packed bf16 (uint4), weighted accumulate into acc[8]
__device__ __forceinline__ void bf8acc(uint4 u, float wgt, float* acc) {
    acc[0] += wgt * __uint_as_float(u.x << 16);
    acc[1] += wgt * __uint_as_float(u.x & 0xffff0000u);
    acc[2] += wgt * __uint_as_float(u.y << 16);
    acc[3] += wgt * __uint_as_float(u.y & 0xffff0000u);
    acc[4] += wgt * __uint_as_float(u.z << 16);
    acc[5] += wgt * __uint_as_float(u.z & 0xffff0000u);
    acc[6] += wgt * __uint_as_float(u.w << 16);
    acc[7] += wgt * __uint_as_float(u.w & 0xffff0000u);
}

// ---------------------------------------------------------------------------
// prep: bf16 weights (O,C) o-major; fused epilogue params
__global__ void k_prep(const float* __restrict__ cw, const float* __restrict__ ipw,
                       const float* __restrict__ offw, const float* __restrict__ maskw,
                       const float* __restrict__ opw,
                       const float* __restrict__ offb, const float* __restrict__ maskb,
                       const float* __restrict__ g1, const float* __restrict__ b1,
                       const float* __restrict__ m1, const float* __restrict__ v1,
                       const float* __restrict__ g2, const float* __restrict__ b2,
                       const float* __restrict__ m2, const float* __restrict__ v2,
                       short* __restrict__ Wc1b, short* __restrict__ Wipb,
                       short* __restrict__ Whb, short* __restrict__ Wopb,
                       float* __restrict__ bh, float* __restrict__ sc1, float* __restrict__ sh1,
                       float* __restrict__ sc2, float* __restrict__ sh2) {
    int o = blockIdx.x, c = threadIdx.x;
    Wc1b[o * CC + c] = f2bf(cw[o * CC + c]);
    Wipb[o * CC + c] = f2bf(ipw[c * CC + o]);
    float hv = 0.f;
    if (o < 144) hv = offw[c * 144 + o];
    else if (o < 216) hv = maskw[c * 72 + (o - 144)];
    Whb[o * CC + c] = f2bf(hv);
    Wopb[o * CC + c] = f2bf(opw[c * CC + o]);
    if (o == 0) {
        float bv = 0.f;
        if (c < 144) bv = offb[c];
        else if (c < 216) bv = maskb[c - 144];
        bh[c] = bv;
        float s1 = g1[c] * rsqrtf(v1[c] + 1e-3f);
        sc1[c] = s1; sh1[c] = b1[c] - m1[c] * s1;
        float s2 = g2[c] * rsqrtf(v2[c] + 1e-5f);
        sc2[c] = s2; sh2[c] = b2[c] - m2[c] * s2;
    }
}

// ---------------------------------------------------------------------------
// wave-level GEMM: 2 n-tiles (32 outputs) per wave, K=256, A rows 0..15 in LDS
__device__ __forceinline__ void gemm2(const short* As, const short* __restrict__ Wb,
                                      int lane, int n0, f32x4 acc[2]) {
    const int m = lane & 15, q = lane >> 4;
#pragma unroll
    for (int kk = 0; kk < 8; ++kk) {
        int c0 = kk * 32 + q * 8;
        short8 a = *(const short8*)(As + m * ASTR + c0);
#pragma unroll
        for (int nt = 0; nt < 2; ++nt) {
            short8 b = *(const short8*)(Wb + (size_t)(n0 + nt * 16 + m) * CC + c0);
            acc[nt] = __builtin_amdgcn_mfma_f32_16x16x32_bf16(a, b, acc[nt], 0, 0, 0);
        }
    }
}

// ---------------------------------------------------------------------------
// conv1(1x1, NCHW) + BN1 + SiLU -> ybf (NHWC bf16) ; fused inproj -> xpb (NHWC bf16)
__global__ __launch_bounds__(512, 4) void k_conv_in(
        const float* __restrict__ x, const short* __restrict__ Wc1b,
        const short* __restrict__ Wipb, const float* __restrict__ sc1,
        const float* __restrict__ sh1, const float* __restrict__ ipb,
        short* __restrict__ ybf, short* __restrict__ xpb) {
    __shared__ __align__(16) short As[MT * ASTR];
    int tid = threadIdx.x, lane = tid & 63, wv = tid >> 6;
    int pix0 = blockIdx.x * MT;
    int n = pix0 >> 12, hw0 = pix0 & (HWSZ - 1);
    int n0 = wv * 32;
    const float* xn = x + (size_t)n * CC * HWSZ;
#pragma unroll
    for (int rep = 0; rep < 2; ++rep) {
        int f = tid + rep * 512;
        int c = f >> 2, i4 = (f & 3) * 4;
        float4 v = *(const float4*)(xn + (size_t)c * HWSZ + hw0 + i4);
        As[(i4 + 0) * ASTR + c] = f2bf(v.x);
        As[(i4 + 1) * ASTR + c] = f2bf(v.y);
        As[(i4 + 2) * ASTR + c] = f2bf(v.z);
        As[(i4 + 3) * ASTR + c] = f2bf(v.w);
    }
    __syncthreads();
    f32x4 acc[2];
    acc[0] = (f32x4){0.f, 0.f, 0.f, 0.f};
    acc[1] = (f32x4){0.f, 0.f, 0.f, 0.f};
    gemm2(As, Wc1b, lane, n0, acc);
    __syncthreads();
    int col = lane & 15, qr = (lane >> 4) * 4;
#pragma unroll
    for (int nt = 0; nt < 2; ++nt) {
        int o = n0 + nt * 16 + col;
        float sc = sc1[o], sh = sh1[o];
#pragma unroll
        for (int r = 0; r < 4; ++r) {
            int pix = qr + r;
            short vb = f2bf(silu_f(acc[nt][r] * sc + sh));
            ybf[(size_t)(pix0 + pix) * CC + o] = vb;
            As[pix * ASTR + o] = vb;
        }
    }
    __syncthreads();
    acc[0] = (f32x4){0.f, 0.f, 0.f, 0.f};
    acc[1] = (f32x4){0.f, 0.f, 0.f, 0.f};
    gemm2(As, Wipb, lane, n0, acc);
#pragma unroll
    for (int nt = 0; nt < 2; ++nt) {
        int o = n0 + nt * 16 + col;
        float bo = ipb[o];
#pragma unroll
        for (int r = 0; r < 4; ++r)
            xpb[(size_t)(pix0 + qr + r) * CC + o] = f2bf(acc[nt][r] + bo);
    }
}

// ---------------------------------------------------------------------------
// fused tail on a 16-pixel row tile, 512 threads (8 waves), 4 barriers.
__global__ __launch_bounds__(512, 6) void k_tail(
        const short* __restrict__ ybf, const short* __restrict__ xpb,
        const float* __restrict__ dww, const float* __restrict__ dwb,
        const float* __restrict__ lng, const float* __restrict__ lnb,
        const short* __restrict__ Whb, const float* __restrict__ bh,
        const short* __restrict__ Wopb, const float* __restrict__ opb,
        const float* __restrict__ sc2, const float* __restrict__ sh2,
        float* __restrict__ out) {
    __shared__ __align__(16) short As[TT * ASTR];
    __shared__ __align__(16) float buf[TT * 260];   // ml/loff, later xs overlay
    float* ml   = buf;              // 16*76
    float* loff = buf + 1216;       // 16*144
    float* xs   = buf;              // 16*260 overlay (phase 5+)

    int tid = threadIdx.x, lane = tid & 63, wv = tid >> 6;
    int pix0 = blockIdx.x * TT;
    int n = pix0 >> 12, hw0 = pix0 & (HWSZ - 1);
    int h = hw0 >> 6, w0 = hw0 & 63;          // 16 pixels share row h
    int c0 = lane * 4;
    int n0 = wv * 32;
    int col = lane & 15, qr = (lane >> 4) * 4;

    // ---- phase 1: dw 3x3 + bias + LN + GELU (2 px/wave, 4 ch/lane, branchless) -> As
    {
        float wloc[36];
        const float4* wp4 = (const float4*)(dww + c0 * 9);
#pragma unroll
        for (int k = 0; k < 9; ++k) ((float4*)wloc)[k] = wp4[k];
        float4 dwbv = *(const float4*)(dwb + c0);
        float4 lngv = *(const float4*)(lng + c0);
        float4 lnbv = *(const float4*)(lnb + c0);
        const short* yn = ybf + (size_t)n * HWSZ * CC;
#pragma unroll
        for (int i = 0; i < 2; ++i) {
            int pix = wv * 2 + i;
            int w = w0 + pix;
            float4 acc = dwbv;
#pragma unroll
            for (int ky = 0; ky < 3; ++ky) {
                int yy = h + ky - 1;
                int yc = min(max(yy, 0), HH - 1);
                float vy = (yy == yc) ? 1.f : 0.f;
#pragma unroll
                for (int kx = 0; kx < 3; ++kx) {
                    int xx = w + kx - 1;
                    int xc = min(max(xx, 0), WW - 1);
                    float vm = vy * ((xx == xc) ? 1.f : 0.f);
                    float4 yv = bf4(*(const uint2*)(yn + (size_t)((yc << 6) + xc) * CC + c0));
                    int t = ky * 3 + kx;
                    acc.x += yv.x * wloc[0 * 9 + t] * vm;
                    acc.y += yv.y * wloc[1 * 9 + t] * vm;
                    acc.z += yv.z * wloc[2 * 9 + t] * vm;
                    acc.w += yv.w * wloc[3 * 9 + t] * vm;
                }
            }
            float s1 = acc.x + acc.y + acc.z + acc.w;
            float s2 = acc.x * acc.x + acc.y * acc.y + acc.z * acc.z + acc.w * acc.w;
#pragma unroll
            for (int off = 32; off > 0; off >>= 1) {
                s1 += __shfl_xor(s1, off);
                s2 += __shfl_xor(s2, off);
            }
            float mu = s1 * (1.f / 256.f);
            float var = s2 * (1.f / 256.f) - mu * mu;
            float rs = rsqrtf(var + 1e-5f);
            float4 zv;
            zv.x = (acc.x - mu) * rs * lngv.x + lnbv.x;
            zv.y = (acc.y - mu) * rs * lngv.y + lnbv.y;
            zv.z = (acc.z - mu) * rs * lngv.z + lnbv.z;
            zv.w = (acc.w - mu) * rs * lngv.w + lnbv.w;
            zv.x = 0.5f * zv.x * (1.f + erff(zv.x * 0.70710678118654752f));
            zv.y = 0.5f * zv.y * (1.f + erff(zv.y * 0.70710678118654752f));
            zv.z = 0.5f * zv.z * (1.f + erff(zv.z * 0.70710678118654752f));
            zv.w = 0.5f * zv.w * (1.f + erff(zv.w * 0.70710678118654752f));
            *(uint2*)(As + pix * ASTR + c0) = make_uint2(pk2(zv.x, zv.y), pk2(zv.z, zv.w));
        }
    }
    __syncthreads();

    // ---- phase 2: heads GEMM -> loff / ml (LDS only)
    {
        f32x4 acc[2];
        acc[0] = (f32x4){0.f, 0.f, 0.f, 0.f};
        acc[1] = (f32x4){0.f, 0.f, 0.f, 0.f};
        gemm2(As, Whb, lane, n0, acc);
#pragma unroll
        for (int nt = 0; nt < 2; ++nt) {
            int o = n0 + nt * 16 + col;
            float bo = bh[o];
#pragma unroll
            for (int r = 0; r < 4; ++r) {
                float v = acc[nt][r] + bo;
                int pix = qr + r;
                if (o < 144) loff[pix * 144 + o] = v;
                else if (o < 216) ml[pix * 76 + (o - 144)] = v;
            }
        }
    }
    __syncthreads();

    // ---- phase 4: per-lane softmax + branchless gather (2 px/wave, 8 ch/lane) -> As
    {
        int ph = lane >> 5;              // pixel half within wave
        int g  = (lane >> 2) & 7;        // group
        int ci = lane & 3;
        int gc0 = g * 32 + ci * 8;       // 8 channels, 16-B aligned
        int pix = wv * 2 + ph;
        int w = w0 + pix;
        float e9[9];
        {
            const float* row = ml + pix * 76 + g * 9;
            float mx = -1e30f;
#pragma unroll
            for (int p = 0; p < 9; ++p) { e9[p] = row[p]; mx = fmaxf(mx, e9[p]); }
            float ssum = 0.f;
#pragma unroll
            for (int p = 0; p < 9; ++p) { e9[p] = __expf(e9[p] - mx); ssum += e9[p]; }
            float inv = 1.f / ssum;
#pragma unroll
            for (int p = 0; p < 9; ++p) e9[p] *= inv;
        }
        const float* lp = loff + pix * 144 + g * 18;
        const short* xpn = xpb + (size_t)n * HWSZ * CC;
        float acc8[8];
#pragma unroll
        for (int k = 0; k < 8; ++k) acc8[k] = 0.f;
#pragma unroll
        for (int p = 0; p < 9; ++p) {
            float ox = lp[p * 2], oy = lp[p * 2 + 1];
            float px = (float)(w + p / 3) + ox;
            float py = (float)(h + p % 3) + oy;
            float fx = floorf(px), fy = floorf(py);
            float wx1 = px - fx, wy1 = py - fy;
            int x0 = (int)fx, y0 = (int)fy;
            int x1 = x0 + 1, y1 = y0 + 1;
            int xc0 = min(max(x0, 1), WW), xc1 = min(max(x1, 1), WW);
            int yc0 = min(max(y0, 1), HH), yc1 = min(max(y1, 1), HH);
            float vx0 = (x0 == xc0) ? 1.f : 0.f, vx1 = (x1 == xc1) ? 1.f : 0.f;
            float vy0 = (y0 == yc0) ? 1.f : 0.f, vy1 = (y1 == yc1) ? 1.f : 0.f;
            float mval = e9[p];
            float w00 = (1.f - wx1) * (1.f - wy1) * mval * vx0 * vy0;
            float w10 = wx1 * (1.f - wy1) * mval * vx1 * vy0;
            float w01 = (1.f - wx1) * wy1 * mval * vx0 * vy1;
            float w11 = wx1 * wy1 * mval * vx1 * vy1;
            uint4 u00 = *(const uint4*)(xpn + (size_t)(((yc0 - 1) << 6) + (xc0 - 1)) * CC + gc0);
            uint4 u10 = *(const uint4*)(xpn + (size_t)(((yc0 - 1) << 6) + (xc1 - 1)) * CC + gc0);
            uint4 u01 = *(const uint4*)(xpn + (size_t)(((yc1 - 1) << 6) + (xc0 - 1)) * CC + gc0);
            uint4 u11 = *(const uint4*)(xpn + (size_t)(((yc1 - 1) << 6) + (xc1 - 1)) * CC + gc0);
            bf8acc(u00, w00, acc8);
            bf8acc(u10, w10, acc8);
            bf8acc(u01, w01, acc8);
            bf8acc(u11, w11, acc8);
        }
        uint4 pkv;
        pkv.x = pk2(acc8[0], acc8[1]);
        pkv.y = pk2(acc8[2], acc8[3]);
        pkv.z = pk2(acc8[4], acc8[5]);
        pkv.w = pk2(acc8[6], acc8[7]);
        *(uint4*)(As + pix * ASTR + gc0) = pkv;
    }
    __syncthreads();

    // ---- phase 5: outproj GEMM + BN2 + SiLU -> xs (overlay)
    {
        f32x4 acc[2];
        acc[0] = (f32x4){0.f, 0.f, 0.f, 0.f};
        acc[1] = (f32x4){0.f, 0.f, 0.f, 0.f};
        gemm2(As, Wopb, lane, n0, acc);
        __syncthreads();   // ml/loff reads done; safe to overlay xs
#pragma unroll
        for (int nt = 0; nt < 2; ++nt) {
            int o = n0 + nt * 16 + col;
            float bo = opb[o], sc = sc2[o], sh = sh2[o];
#pragma unroll
            for (int r = 0; r < 4; ++r)
                xs[(qr + r) * 260 + o] = silu_f((acc[nt][r] + bo) * sc + sh);
        }
    }
    __syncthreads();

    // ---- store NCHW: 4 lanes cover one channel's 16 pixels = one 64-B line
    {
        int i4 = (tid & 3) * 4;
        int obase = tid >> 2;                 // 0..127
        float* on = out + (size_t)n * CC * HWSZ + hw0 + i4;
#pragma unroll
        for (int pass = 0; pass < 2; ++pass) {
            int o = obase + pass * 128;
            float4 ov;
            ov.x = xs[(i4 + 0) * 260 + o];
            ov.y = xs[(i4 + 1) * 260 + o];
            ov.z = xs[(i4 + 2) * 260 + o];
            ov.w = xs[(i4 + 3) * 260 + o];
            *(float4*)(on + (size_t)o * HWSZ) = ov;
        }
    }
}

// ---------------------------------------------------------------------------
extern "C" void kernel_launch(void* const* d_in, const int* in_sizes, int n_in,
                              void* d_out, int out_size, void* d_ws, size_t ws_size,
                              hipStream_t stream) {
    const float* x        = (const float*)d_in[0];
    const float* conv1_w  = (const float*)d_in[1];
    const float* bn1_g    = (const float*)d_in[2];
    const float* bn1_b    = (const float*)d_in[3];
    const float* bn1_m    = (const float*)d_in[4];
    const float* bn1_v    = (const float*)d_in[5];
    const float* inproj_w = (const float*)d_in[6];
    const float* inproj_b = (const float*)d_in[7];
    const float* dw_w     = (const float*)d_in[8];
    const float* dw_b     = (const float*)d_in[9];
    const float* ln_g     = (const float*)d_in[10];
    const float* ln_b     = (const float*)d_in[11];
    const float* off_w    = (const float*)d_in[12];
    const float* off_b    = (const float*)d_in[13];
    const float* mask_w   = (const float*)d_in[14];
    const float* mask_b   = (const float*)d_in[15];
    const float* outproj_w = (const float*)d_in[16];
    const float* outproj_b = (const float*)d_in[17];
    const float* bn2_g    = (const float*)d_in[18];
    const float* bn2_b    = (const float*)d_in[19];
    const float* bn2_m    = (const float*)d_in[20];
    const float* bn2_v    = (const float*)d_in[21];
    float* out = (float*)d_out;

    short* Wc1b = (short*)d_ws;            // 65536 shorts each
    short* Wipb = Wc1b + 65536;
    short* Whb  = Wipb + 65536;
    short* Wopb = Whb + 65536;
    float* fp   = (float*)(Wopb + 65536);
    float* bh   = fp;
    float* sc1  = bh + 256;
    float* sh1  = sc1 + 256;
    float* sc2  = sh1 + 256;
    float* sh2  = sc2 + 256;
    short* ybf  = (short*)(sh2 + 256);     // NPIX*CC bf16 (NHWC)
    short* xpb  = ybf + (size_t)NPIX * CC; // NPIX*CC bf16 (NHWC)

    k_prep<<<dim3(CC), dim3(CC), 0, stream>>>(conv1_w, inproj_w, off_w, mask_w, outproj_w,
                                              off_b, mask_b, bn1_g, bn1_b, bn1_m, bn1_v,
                                              bn2_g, bn2_b, bn2_m, bn2_v,
                                              Wc1b, Wipb, Whb, Wopb, bh, sc1, sh1, sc2, sh2);
    k_conv_in<<<dim3(NPIX / MT), dim3(512), 0, stream>>>(x, Wc1b, Wipb, sc1, sh1, inproj_b, ybf, xpb);
    k_tail<<<dim3(NPIX / TT), dim3(512), 0, stream>>>(ybf, xpb, dw_w, dw_b, ln_g, ln_b,
                                                      Whb, bh, Wopb, outproj_b, sc2, sh2, out);
}

// Round 9
// 151.985 us; speedup vs baseline: 1.1729x; 1.1729x over previous
//
#include <hip/hip_runtime.h>
#include <math.h>

// Problem constants (N=2, C=256, H=W=64, G=8, P=9, CG=32)
#define CC    256
#define HH    64
#define WW    64
#define HWSZ  4096
#define NPIX  8192
#define MT    16        // conv_in tile (pixels)
#define TT    16        // tail tile (pixels)
#define ASTR  264       // A-tile LDS row stride in bf16 elems (528 B)

typedef __attribute__((ext_vector_type(8))) short short8;
typedef __attribute__((ext_vector_type(4))) float f32x4;

__device__ __forceinline__ float silu_f(float x) { return x / (1.f + __expf(-x)); }

// fp32 -> bf16 round-to-nearest-even
__device__ __forceinline__ short f2bf(float f) {
    unsigned u = __float_as_uint(f);
    unsigned r = (u + 0x7fffu + ((u >> 16) & 1u)) >> 16;
    return (short)r;
}
__device__ __forceinline__ unsigned pk2(float a, float b) {
    return (unsigned)(unsigned short)f2bf(a) | ((unsigned)(unsigned short)f2bf(b) << 16);
}
// 4 packed bf16 -> float4
__device__ __forceinline__ float4 bf4(uint2 u) {
    float4 r;
    r.x = __uint_as_float(u.x << 16);
    r.y = __uint_as_float(u.x & 0xffff0000u);
    r.z = __uint_as_float(u.y << 16);
    r.w = __uint_as_float(u.y & 0xffff0000u);
    return r;
}
// 8 packed bf16 (uint4), weighted accumulate into acc[8]
__device__ __forceinline__ void bf8acc(uint4 u, float wgt, float* acc) {
    acc[0] += wgt * __uint_as_float(u.x << 16);
    acc[1] += wgt * __uint_as_float(u.x & 0xffff0000u);
    acc[2] += wgt * __uint_as_float(u.y << 16);
    acc[3] += wgt * __uint_as_float(u.y & 0xffff0000u);
    acc[4] += wgt * __uint_as_float(u.z << 16);
    acc[5] += wgt * __uint_as_float(u.z & 0xffff0000u);
    acc[6] += wgt * __uint_as_float(u.w << 16);
    acc[7] += wgt * __uint_as_float(u.w & 0xffff0000u);
}

// ---------------------------------------------------------------------------
// prep: bf16 weights (O,C) o-major; dw weights transposed to [tap][c]; epilogue params
__global__ void k_prep(const float* __restrict__ cw, const float* __restrict__ ipw,
                       const float* __restrict__ offw, const float* __restrict__ maskw,
                       const float* __restrict__ opw, const float* __restrict__ dww,
                       const float* __restrict__ offb, const float* __restrict__ maskb,
                       const float* __restrict__ g1, const float* __restrict__ b1,
                       const float* __restrict__ m1, const float* __restrict__ v1,
                       const float* __restrict__ g2, const float* __restrict__ b2,
                       const float* __restrict__ m2, const float* __restrict__ v2,
                       short* __restrict__ Wc1b, short* __restrict__ Wipb,
                       short* __restrict__ Whb, short* __restrict__ Wopb,
                       float* __restrict__ dwt,
                       float* __restrict__ bh, float* __restrict__ sc1, float* __restrict__ sh1,
                       float* __restrict__ sc2, float* __restrict__ sh2) {
    int o = blockIdx.x, c = threadIdx.x;
    Wc1b[o * CC + c] = f2bf(cw[o * CC + c]);
    Wipb[o * CC + c] = f2bf(ipw[c * CC + o]);
    float hv = 0.f;
    if (o < 144) hv = offw[c * 144 + o];
    else if (o < 216) hv = maskw[c * 72 + (o - 144)];
    Whb[o * CC + c] = f2bf(hv);
    Wopb[o * CC + c] = f2bf(opw[c * CC + o]);
    if (o < 9) dwt[o * CC + c] = dww[c * 9 + o];
    if (o == 0) {
        float bv = 0.f;
        if (c < 144) bv = offb[c];
        else if (c < 216) bv = maskb[c - 144];
        bh[c] = bv;
        float s1 = g1[c] * rsqrtf(v1[c] + 1e-3f);
        sc1[c] = s1; sh1[c] = b1[c] - m1[c] * s1;
        float s2 = g2[c] * rsqrtf(v2[c] + 1e-5f);
        sc2[c] = s2; sh2[c] = b2[c] - m2[c] * s2;
    }
}

// ---------------------------------------------------------------------------
// wave-level GEMM: 2 n-tiles (32 outputs) per wave, K=256, A rows 0..15 in LDS
__device__ __forceinline__ void gemm2(const short* As, const short* __restrict__ Wb,
                                      int lane, int n0, f32x4 acc[2]) {
    const int m = lane & 15, q = lane >> 4;
#pragma unroll
    for (int kk = 0; kk < 8; ++kk) {
        int c0 = kk * 32 + q * 8;
        short8 a = *(const short8*)(As + m * ASTR + c0);
#pragma unroll
        for (int nt = 0; nt < 2; ++nt) {
            short8 b = *(const short8*)(Wb + (size_t)(n0 + nt * 16 + m) * CC + c0);
            acc[nt] = __builtin_amdgcn_mfma_f32_16x16x32_bf16(a, b, acc[nt], 0, 0, 0);
        }
    }
}

// ---------------------------------------------------------------------------
// conv1(1x1, NCHW) + BN1 + SiLU -> ybf (NHWC bf16) ; fused inproj -> xpb (NHWC bf16)
__global__ __launch_bounds__(512, 4) void k_conv_in(
        const float* __restrict__ x, const short* __restrict__ Wc1b,
        const short* __restrict__ Wipb, const float* __restrict__ sc1,
        const float* __restrict__ sh1, const float* __restrict__ ipb,
        short* __restrict__ ybf, short* __restrict__ xpb) {
    __shared__ __align__(16) short As[MT * ASTR];
    int tid = threadIdx.x, lane = tid & 63, wv = tid >> 6;
    int pix0 = blockIdx.x * MT;
    int n = pix0 >> 12, hw0 = pix0 & (HWSZ - 1);
    int n0 = wv * 32;
    const float* xn = x + (size_t)n * CC * HWSZ;
#pragma unroll
    for (int rep = 0; rep < 2; ++rep) {
        int f = tid + rep * 512;
        int c = f >> 2, i4 = (f & 3) * 4;
        float4 v = *(const float4*)(xn + (size_t)c * HWSZ + hw0 + i4);
        As[(i4 + 0) * ASTR + c] = f2bf(v.x);
        As[(i4 + 1) * ASTR + c] = f2bf(v.y);
        As[(i4 + 2) * ASTR + c] = f2bf(v.z);
        As[(i4 + 3) * ASTR + c] = f2bf(v.w);
    }
    __syncthreads();
    f32x4 acc[2];
    acc[0] = (f32x4){0.f, 0.f, 0.f, 0.f};
    acc[1] = (f32x4){0.f, 0.f, 0.f, 0.f};
    gemm2(As, Wc1b, lane, n0, acc);
    __syncthreads();
    int col = lane & 15, qr = (lane >> 4) * 4;
#pragma unroll
    for (int nt = 0; nt < 2; ++nt) {
        int o = n0 + nt * 16 + col;
        float sc = sc1[o], sh = sh1[o];
#pragma unroll
        for (int r = 0; r < 4; ++r) {
            int pix = qr + r;
            short vb = f2bf(silu_f(acc[nt][r] * sc + sh));
            ybf[(size_t)(pix0 + pix) * CC + o] = vb;
            As[pix * ASTR + o] = vb;
        }
    }
    __syncthreads();
    acc[0] = (f32x4){0.f, 0.f, 0.f, 0.f};
    acc[1] = (f32x4){0.f, 0.f, 0.f, 0.f};
    gemm2(As, Wipb, lane, n0, acc);
#pragma unroll
    for (int nt = 0; nt < 2; ++nt) {
        int o = n0 + nt * 16 + col;
        float bo = ipb[o];
#pragma unroll
        for (int r = 0; r < 4; ++r)
            xpb[(size_t)(pix0 + qr + r) * CC + o] = f2bf(acc[nt][r] + bo);
    }
}

// ---------------------------------------------------------------------------
// fused tail on a 16-pixel row tile, 512 threads (8 waves), 4 barriers.
// launch_bounds (512,4): 128-VGPR budget so NO private arrays spill to scratch.
__global__ __launch_bounds__(512, 4) void k_tail(
        const short* __restrict__ ybf, const short* __restrict__ xpb,
        const float* __restrict__ dwt, const float* __restrict__ dwb,
        const float* __restrict__ lng, const float* __restrict__ lnb,
        const short* __restrict__ Whb, const float* __restrict__ bh,
        const short* __restrict__ Wopb, const float* __restrict__ opb,
        const float* __restrict__ sc2, const float* __restrict__ sh2,
        float* __restrict__ out) {
    __shared__ __align__(16) short As[TT * ASTR];
    __shared__ __align__(16) float buf[TT * 260];   // ml/loff, later xs overlay
    float* ml   = buf;              // 16*76
    float* loff = buf + 1216;       // 16*144
    float* xs   = buf;              // 16*260 overlay (phase 5+)

    int tid = threadIdx.x, lane = tid & 63, wv = tid >> 6;
    int pix0 = blockIdx.x * TT;
    int n = pix0 >> 12, hw0 = pix0 & (HWSZ - 1);
    int h = hw0 >> 6, w0 = hw0 & 63;          // 16 pixels share row h
    int c0 = lane * 4;
    int n0 = wv * 32;
    int col = lane & 15, qr = (lane >> 4) * 4;

    // ---- phase 1: dw 3x3 + bias + LN + GELU (2 px/wave, 4 ch/lane) -> As
    // dw weights loaded per-tap from transposed [t][c] layout (coalesced, L2-hot).
    {
        float4 dwbv = *(const float4*)(dwb + c0);
        float4 lngv = *(const float4*)(lng + c0);
        float4 lnbv = *(const float4*)(lnb + c0);
        const short* yn = ybf + (size_t)n * HWSZ * CC;
#pragma unroll
        for (int i = 0; i < 2; ++i) {
            int pix = wv * 2 + i;
            int w = w0 + pix;
            float4 acc = dwbv;
#pragma unroll
            for (int ky = 0; ky < 3; ++ky) {
                int yy = h + ky - 1;
                int yc = min(max(yy, 0), HH - 1);
                float vy = (yy == yc) ? 1.f : 0.f;
#pragma unroll
                for (int kx = 0; kx < 3; ++kx) {
                    int xx = w + kx - 1;
                    int xc = min(max(xx, 0), WW - 1);
                    float vm = vy * ((xx == xc) ? 1.f : 0.f);
                    int t = ky * 3 + kx;
                    float4 wt = *(const float4*)(dwt + t * CC + c0);
                    float4 yv = bf4(*(const uint2*)(yn + (size_t)((yc << 6) + xc) * CC + c0));
                    acc.x += yv.x * wt.x * vm;
                    acc.y += yv.y * wt.y * vm;
                    acc.z += yv.z * wt.z * vm;
                    acc.w += yv.w * wt.w * vm;
                }
            }
            float s1 = acc.x + acc.y + acc.z + acc.w;
            float s2 = acc.x * acc.x + acc.y * acc.y + acc.z * acc.z + acc.w * acc.w;
#pragma unroll
            for (int off = 32; off > 0; off >>= 1) {
                s1 += __shfl_xor(s1, off);
                s2 += __shfl_xor(s2, off);
            }
            float mu = s1 * (1.f / 256.f);
            float var = s2 * (1.f / 256.f) - mu * mu;
            float rs = rsqrtf(var + 1e-5f);
            float4 zv;
            zv.x = (acc.x - mu) * rs * lngv.x + lnbv.x;
            zv.y = (acc.y - mu) * rs * lngv.y + lnbv.y;
            zv.z = (acc.z - mu) * rs * lngv.z + lnbv.z;
            zv.w = (acc.w - mu) * rs * lngv.w + lnbv.w;
            zv.x = 0.5f * zv.x * (1.f + erff(zv.x * 0.70710678118654752f));
            zv.y = 0.5f * zv.y * (1.f + erff(zv.y * 0.70710678118654752f));
            zv.z = 0.5f * zv.z * (1.f + erff(zv.z * 0.70710678118654752f));
            zv.w = 0.5f * zv.w * (1.f + erff(zv.w * 0.70710678118654752f));
            *(uint2*)(As + pix * ASTR + c0) = make_uint2(pk2(zv.x, zv.y), pk2(zv.z, zv.w));
        }
    }
    __syncthreads();

    // ---- phase 2: heads GEMM -> loff / ml (LDS only)
    {
        f32x4 acc[2];
        acc[0] = (f32x4){0.f, 0.f, 0.f, 0.f};
        acc[1] = (f32x4){0.f, 0.f, 0.f, 0.f};
        gemm2(As, Whb, lane, n0, acc);
#pragma unroll
        for (int nt = 0; nt < 2; ++nt) {
            int o = n0 + nt * 16 + col;
            float bo = bh[o];
#pragma unroll
            for (int r = 0; r < 4; ++r) {
                float v = acc[nt][r] + bo;
                int pix = qr + r;
                if (o < 144) loff[pix * 144 + o] = v;
                else if (o < 216) ml[pix * 76 + (o - 144)] = v;
            }
        }
    }
    __syncthreads();

    // ---- phase 4: per-lane softmax + branchless gather (2 px/wave, 8 ch/lane) -> As
    {
        int ph = lane >> 5;              // pixel half within wave
        int g  = (lane >> 2) & 7;        // group
        int ci = lane & 3;
        int gc0 = g * 32 + ci * 8;       // 8 channels, 16-B aligned
        int pix = wv * 2 + ph;
        int w = w0 + pix;
        float e9[9];
        {
            const float* row = ml + pix * 76 + g * 9;
            float mx = -1e30f;
#pragma unroll
            for (int p = 0; p < 9; ++p) { e9[p] = row[p]; mx = fmaxf(mx, e9[p]); }
            float ssum = 0.f;
#pragma unroll
            for (int p = 0; p < 9; ++p) { e9[p] = __expf(e9[p] - mx); ssum += e9[p]; }
            float inv = 1.f / ssum;
#pragma unroll
            for (int p = 0; p < 9; ++p) e9[p] *= inv;
        }
        const float* lp = loff + pix * 144 + g * 18;
        const short* xpn = xpb + (size_t)n * HWSZ * CC;
        float acc8[8];
#pragma unroll
        for (int k = 0; k < 8; ++k) acc8[k] = 0.f;
#pragma unroll
        for (int p = 0; p < 9; ++p) {
            float ox = lp[p * 2], oy = lp[p * 2 + 1];
            float px = (float)(w + p / 3) + ox;
            float py = (float)(h + p % 3) + oy;
            float fx = floorf(px), fy = floorf(py);
            float wx1 = px - fx, wy1 = py - fy;
            int x0 = (int)fx, y0 = (int)fy;
            int x1 = x0 + 1, y1 = y0 + 1;
            int xc0 = min(max(x0, 1), WW), xc1 = min(max(x1, 1), WW);
            int yc0 = min(max(y0, 1), HH), yc1 = min(max(y1, 1), HH);
            float vx0 = (x0 == xc0) ? 1.f : 0.f, vx1 = (x1 == xc1) ? 1.f : 0.f;
            float vy0 = (y0 == yc0) ? 1.f : 0.f, vy1 = (y1 == yc1) ? 1.f : 0.f;
            float mval = e9[p];
            float w00 = (1.f - wx1) * (1.f - wy1) * mval * vx0 * vy0;
            float w10 = wx1 * (1.f - wy1) * mval * vx1 * vy0;
            float w01 = (1.f - wx1) * wy1 * mval * vx0 * vy1;
            float w11 = wx1 * wy1 * mval * vx1 * vy1;
            uint4 u00 = *(const uint4*)(xpn + (size_t)(((yc0 - 1) << 6) + (xc0 - 1)) * CC + gc0);
            uint4 u10 = *(const uint4*)(xpn + (size_t)(((yc0 - 1) << 6) + (xc1 - 1)) * CC + gc0);
            uint4 u01 = *(const uint4*)(xpn + (size_t)(((yc1 - 1) << 6) + (xc0 - 1)) * CC + gc0);
            uint4 u11 = *(const uint4*)(xpn + (size_t)(((yc1 - 1) << 6) + (xc1 - 1)) * CC + gc0);
            bf8acc(u00, w00, acc8);
            bf8acc(u10, w10, acc8);
            bf8acc(u01, w01, acc8);
            bf8acc(u11, w11, acc8);
        }
        uint4 pkv;
        pkv.x = pk2(acc8[0], acc8[1]);
        pkv.y = pk2(acc8[2], acc8[3]);
        pkv.z = pk2(acc8[4], acc8[5]);
        pkv.w = pk2(acc8[6], acc8[7]);
        *(uint4*)(As + pix * ASTR + gc0) = pkv;
    }
    __syncthreads();    // As v2 ready; ml/loff fully consumed

    // ---- phase 5: outproj GEMM + BN2 + SiLU -> xs (overlay of ml/loff)
    {
        f32x4 acc[2];
        acc[0] = (f32x4){0.f, 0.f, 0.f, 0.f};
        acc[1] = (f32x4){0.f, 0.f, 0.f, 0.f};
        gemm2(As, Wopb, lane, n0, acc);
#pragma unroll
        for (int nt = 0; nt < 2; ++nt) {
            int o = n0 + nt * 16 + col;
            float bo = opb[o], sc = sc2[o], sh = sh2[o];
#pragma unroll
            for (int r = 0; r < 4; ++r)
                xs[(qr + r) * 260 + o] = silu_f((acc[nt][r] + bo) * sc + sh);
        }
    }
    __syncthreads();

    // ---- store NCHW: 4 lanes cover one channel's 16 pixels = one 64-B line
    {
        int i4 = (tid & 3) * 4;
        int obase = tid >> 2;                 // 0..127
        float* on = out + (size_t)n * CC * HWSZ + hw0 + i4;
#pragma unroll
        for (int pass = 0; pass < 2; ++pass) {
            int o = obase + pass * 128;
            float4 ov;
            ov.x = xs[(i4 + 0) * 260 + o];
            ov.y = xs[(i4 + 1) * 260 + o];
            ov.z = xs[(i4 + 2) * 260 + o];
            ov.w = xs[(i4 + 3) * 260 + o];
            *(float4*)(on + (size_t)o * HWSZ) = ov;
        }
    }
}

// ---------------------------------------------------------------------------
extern "C" void kernel_launch(void* const* d_in, const int* in_sizes, int n_in,
                              void* d_out, int out_size, void* d_ws, size_t ws_size,
                              hipStream_t stream) {
    const float* x        = (const float*)d_in[0];
    const float* conv1_w  = (const float*)d_in[1];
    const float* bn1_g    = (const float*)d_in[2];
    const float* bn1_b    = (const float*)d_in[3];
    const float* bn1_m    = (const float*)d_in[4];
    const float* bn1_v    = (const float*)d_in[5];
    const float* inproj_w = (const float*)d_in[6];
    const float* inproj_b = (const float*)d_in[7];
    const float* dw_w     = (const float*)d_in[8];
    const float* dw_b     = (const float*)d_in[9];
    const float* ln_g     = (const float*)d_in[10];
    const float* ln_b     = (const float*)d_in[11];
    const float* off_w    = (const float*)d_in[12];
    const float* off_b    = (const float*)d_in[13];
    const float* mask_w   = (const float*)d_in[14];
    const float* mask_b   = (const float*)d_in[15];
    const float* outproj_w = (const float*)d_in[16];
    const float* outproj_b = (const float*)d_in[17];
    const float* bn2_g    = (const float*)d_in[18];
    const float* bn2_b    = (const float*)d_in[19];
    const float* bn2_m    = (const float*)d_in[20];
    const float* bn2_v    = (const float*)d_in[21];
    float* out = (float*)d_out;

    short* Wc1b = (short*)d_ws;            // 65536 shorts each
    short* Wipb = Wc1b + 65536;
    short* Whb  = Wipb + 65536;
    short* Wopb = Whb + 65536;
    float* fp   = (float*)(Wopb + 65536);
    float* dwt  = fp;                      // 9*256
    float* bh   = dwt + 9 * CC;
    float* sc1  = bh + 256;
    float* sh1  = sc1 + 256;
    float* sc2  = sh1 + 256;
    float* sh2  = sc2 + 256;
    short* ybf  = (short*)(sh2 + 256);     // NPIX*CC bf16 (NHWC)
    short* xpb  = ybf + (size_t)NPIX * CC; // NPIX*CC bf16 (NHWC)

    k_prep<<<dim3(CC), dim3(CC), 0, stream>>>(conv1_w, inproj_w, off_w, mask_w, outproj_w, dw_w,
                                              off_b, mask_b, bn1_g, bn1_b, bn1_m, bn1_v,
                                              bn2_g, bn2_b, bn2_m, bn2_v,
                                              Wc1b, Wipb, Whb, Wopb, dwt, bh, sc1, sh1, sc2, sh2);
    k_conv_in<<<dim3(NPIX / MT), dim3(512), 0, stream>>>(x, Wc1b, Wipb, sc1, sh1, inproj_b, ybf, xpb);
    k_tail<<<dim3(NPIX / TT), dim3(512), 0, stream>>>(ybf, xpb, dwt, dw_b, ln_g, ln_b,
                                                      Whb, bh, Wopb, outproj_b, sc2, sh2, out);
}